// Round 17
// baseline (269.778 us; speedup 1.0000x reference)
//
#include <hip/hip_runtime.h>
#include <hip/hip_bf16.h>
#include <hip/hip_cooperative_groups.h>

namespace cg = cooperative_groups;

// PGExplainer edge mask.  (R17 = R15 numerics; edge_value+symmetrize fused
// into ONE cooperative kernel with grid.sync() between phases — random
// working sets (Pbot 2.56MB / row16 3.2MB) stay time-separated, one
// dispatch boundary removed. R16 nt-hints REVERTED (regressed 61.7->67.4).
//  FAILED experiments, do not retry: R10 same-time fusion (L2 union 8.5MB),
//  R11 2-edge/thread edge_value, R12 Bloom atomicOr bitmap, R16 nt hints.)
//  1) f12@W1 factorized: P_top = embed@W1[:64]+b1, P_bot = embed@W1[64:]
//     (LDS-tiled fp32 GEMM; k-loop unroll LIMITED to 2 — full spills).
//     rowptr + row16 duties ride as trailing blocks (independent of GEMM).
//  2) keys (col*n+row) sorted ascending (np.unique) -> argsort is identity.
//     Reverse lookup via CSR rowptr + interpolation-guess + local scan.
//  3) sigmoid(log(u)-log1p(-u)+la) == u / (u + (1-u)*exp(-la)).
//  4) Pair-canonical symmetrize: only c<r searches; matches (~800 pairs)
//     exchange fp32 values directly through out[] (disjoint, race-free).

typedef __attribute__((ext_vector_type(2))) float f32x2;

#define EPAD 68   // embed-tile row stride (floats): 16B-aligned, bank-spread

__global__ __launch_bounds__(256) void precompute_kernel(
        const float* __restrict__ embed,
        const float* __restrict__ W1,
        const float* __restrict__ b1,
        unsigned* __restrict__ Ptop,          // fp8 e4m3, 16 u32 per node
        unsigned* __restrict__ Pbot,          // fp8 e4m3, 16 u32 per node
        const int* __restrict__ col,
        const int* __restrict__ row,
        int* __restrict__ rowptr,
        unsigned short* __restrict__ row16,
        int n_nodes, int n_edges, int gemm_blocks, int rp_blocks) {
    int t = threadIdx.x;
    int bid = blockIdx.x;

    if (bid >= gemm_blocks + rp_blocks) {
        // ---- row16 duty: row16[e] = (u16)row[e], 8 edges/thread ----
        int gt = (bid - gemm_blocks - rp_blocks) * 256 + t;
        int e8 = gt * 8;
        if (e8 + 7 < n_edges) {
            int4 r0 = ((const int4*)(row + e8))[0];
            int4 r1 = ((const int4*)(row + e8))[1];
            uint4 packed;
            packed.x = (unsigned)r0.x | ((unsigned)r0.y << 16);
            packed.y = (unsigned)r0.z | ((unsigned)r0.w << 16);
            packed.z = (unsigned)r1.x | ((unsigned)r1.y << 16);
            packed.w = (unsigned)r1.z | ((unsigned)r1.w << 16);
            *(uint4*)(row16 + e8) = packed;
        } else {
            for (int e = e8; e < n_edges; ++e) row16[e] = (unsigned short)row[e];
        }
        return;
    }
    if (bid >= gemm_blocks) {
        // ---- rowptr duty: rowptr[v] = lower_bound(col, v) ----
        int v = (bid - gemm_blocks) * 256 + t;
        if (v <= n_nodes) {
            int lo = 0, hi = n_edges;
            while (lo < hi) {
                int mid = (lo + hi) >> 1;
                if (col[mid] < v) lo = mid + 1; else hi = mid;
            }
            rowptr[v] = lo;
        }
        return;
    }

    __shared__ float W1s[128 * 64];     // 32 KB
    __shared__ float E[64 * EPAD];      // 17.4 KB
    int base = bid * 64;

#pragma unroll
    for (int i = 0; i < 8; ++i) {
        int idx = i * 256 + t;
        ((float4*)W1s)[idx] = ((const float4*)W1)[idx];
    }
#pragma unroll
    for (int i = 0; i < 4; ++i) {
        int fi = i * 256 + t;
        int n = fi >> 4;
        int k4 = (fi & 15) * 4;
        float4 v;
        if (base + n < n_nodes)
            v = ((const float4*)(embed + (size_t)(base + n) * 64))[fi & 15];
        else
            v = make_float4(0.f, 0.f, 0.f, 0.f);
        *((float4*)(E + n * EPAD + k4)) = v;
    }
    __syncthreads();

    int tj = t & 15, tn = t >> 4;
    int j4 = tj * 4, n4 = tn * 4;
    float4 b1v = *(const float4*)(b1 + j4);
    float4 at[4], ab[4];
#pragma unroll
    for (int i = 0; i < 4; ++i) {
        at[i] = b1v;
        ab[i] = make_float4(0.f, 0.f, 0.f, 0.f);
    }

    // unroll 2 ONLY: full unroll hoists ~768 floats of LDS loads -> spill
#pragma unroll 2
    for (int k4 = 0; k4 < 64; k4 += 4) {
        float4 e[4], wt[4], wb[4];
#pragma unroll
        for (int i = 0; i < 4; ++i) {
            e[i]  = *(const float4*)(E + (n4 + i) * EPAD + k4);
            wt[i] = *(const float4*)(W1s + (k4 + i) * 64 + j4);
            wb[i] = *(const float4*)(W1s + (64 + k4 + i) * 64 + j4);
        }
#pragma unroll
        for (int n = 0; n < 4; ++n) {
#pragma unroll
            for (int kk = 0; kk < 4; ++kk) {
                float ev = (kk == 0) ? e[n].x : (kk == 1) ? e[n].y
                         : (kk == 2) ? e[n].z : e[n].w;
                at[n].x += ev * wt[kk].x;  at[n].y += ev * wt[kk].y;
                at[n].z += ev * wt[kk].z;  at[n].w += ev * wt[kk].w;
                ab[n].x += ev * wb[kk].x;  ab[n].y += ev * wb[kk].y;
                ab[n].z += ev * wb[kk].z;  ab[n].w += ev * wb[kk].w;
            }
        }
    }

#pragma unroll
    for (int i = 0; i < 4; ++i) {
        int node = base + n4 + i;
        if (node >= n_nodes) break;
        int wt8 = __builtin_amdgcn_cvt_pk_fp8_f32(at[i].x, at[i].y, 0, false);
        wt8     = __builtin_amdgcn_cvt_pk_fp8_f32(at[i].z, at[i].w, wt8, true);
        Ptop[(size_t)node * 16 + tj] = (unsigned)wt8;
        int wb8 = __builtin_amdgcn_cvt_pk_fp8_f32(ab[i].x, ab[i].y, 0, false);
        wb8     = __builtin_amdgcn_cvt_pk_fp8_f32(ab[i].z, ab[i].w, wb8, true);
        Pbot[(size_t)node * 16 + tj] = (unsigned)wb8;
    }
}

// 4 relu-dot terms from one fp8-quad word per side, packed f32x2 math
#define DOTW(au, bu, wp, acc0, acc1) do {                             \
    f32x2 alo = __builtin_amdgcn_cvt_pk_f32_fp8((au), false);         \
    f32x2 ahi = __builtin_amdgcn_cvt_pk_f32_fp8((au), true);          \
    f32x2 blo = __builtin_amdgcn_cvt_pk_f32_fp8((bu), false);         \
    f32x2 bhi = __builtin_amdgcn_cvt_pk_f32_fp8((bu), true);          \
    f32x2 s0 = alo + blo, s1 = ahi + bhi;                             \
    s0 = __builtin_elementwise_max(s0, (f32x2)0.f);                   \
    s1 = __builtin_elementwise_max(s1, (f32x2)0.f);                   \
    acc0 += s0 * ((const f32x2*)(wp))[0];                             \
    acc1 += s1 * ((const f32x2*)(wp))[1];                             \
} while (0)

__global__ __launch_bounds__(256) void edge_sym_kernel(
        const uint4* __restrict__ Ptop,   // fp8x16 per node
        const uint4* __restrict__ Pbot,
        const float* __restrict__ W2,
        const float* __restrict__ b2,
        const float* __restrict__ noise,
        const int* __restrict__ col,
        const unsigned short* __restrict__ row16,
        const int* __restrict__ rowptr,
        float* __restrict__ out,
        int n_edges, float inv_n) {
    cg::grid_group grid = cg::this_grid();
    int T   = gridDim.x * 256;
    int tid = blockIdx.x * 256 + threadIdx.x;
    float b2v = b2[0];

    // ---- phase A: per-edge MLP value; out[e] = 0.5*v (v if diagonal) ----
    for (int e = tid; e < n_edges; e += T) {
        int c = col[e];
        int r = row16[e];
        float u = noise[e];
        const uint4* pt = Ptop + (size_t)c * 4;
        const uint4* pb = Pbot + (size_t)r * 4;
        f32x2 acc0 = {b2v, 0.f}, acc1 = {0.f, 0.f};
        f32x2 acc2 = {0.f, 0.f}, acc3 = {0.f, 0.f};
#pragma unroll
        for (int g = 0; g < 4; ++g) {
            uint4 a = pt[g];
            uint4 b = pb[g];
            const float* w = W2 + g * 16;
            DOTW(a.x, b.x, w,      acc0, acc1);
            DOTW(a.y, b.y, w + 4,  acc2, acc3);
            DOTW(a.z, b.z, w + 8,  acc0, acc1);
            DOTW(a.w, b.w, w + 12, acc2, acc3);
        }
        f32x2 acc = (acc0 + acc1) + (acc2 + acc3);
        float la = acc.x + acc.y;
        float v = u / (u + (1.f - u) * __expf(-la));
        out[e] = (c == r) ? v : 0.5f * v;
    }

    __threadfence();      // make out[] device-visible across XCDs
    grid.sync();

    // ---- phase B: pair-canonical symmetrize (only c < r searches) ----
    for (int e = tid; e < n_edges; e += T) {
        int c = col[e];
        int r = row16[e];
        if (c >= r) continue;
        int lo = rowptr[r], hi = rowptr[r + 1];
        if (lo >= hi) continue;
        int g = lo + (int)((float)c * (float)(hi - lo) * inv_n);
        if (g >= hi) g = hi - 1;
        int rv = row16[g];
        int match = -1;
        if (rv < c) {
            while (++g < hi) { rv = row16[g]; if (rv >= c) break; }
            if (g < hi && rv == c) match = g;
        } else {
            while (rv > c && g > lo) rv = row16[--g];
            if (rv == c) match = g;
        }
        if (match >= 0) {
            // partner is non-canonical -> never writes here; pairs disjoint
            float mine   = out[e];        // 0.5 * v_fwd
            float theirs = out[match];    // 0.5 * v_rev
            out[e]     = mine + theirs;
            out[match] = theirs + mine;
        }
    }
}

extern "C" void kernel_launch(void* const* d_in, const int* in_sizes, int n_in,
                              void* d_out, int out_size, void* d_ws, size_t ws_size,
                              hipStream_t stream) {
    const float* embed = (const float*)d_in[0];
    const float* W1    = (const float*)d_in[1];
    const float* b1    = (const float*)d_in[2];
    const float* W2    = (const float*)d_in[3];
    const float* b2    = (const float*)d_in[4];
    const float* noise = (const float*)d_in[5];
    const int*   col   = (const int*)d_in[6];
    const int*   row   = (const int*)d_in[7];

    int n_nodes = in_sizes[0] / 64;   // 40000
    int n_edges = in_sizes[5];        // 1600000
    float* out = (float*)d_out;

    char* ws = (char*)d_ws;
    size_t p_sz   = (size_t)n_nodes * 16 * sizeof(unsigned);   // 2.56 MB each
    size_t e16_sz = (size_t)n_edges * sizeof(unsigned short);  // 3.2 MB
    unsigned*       Ptop   = (unsigned*)ws;
    unsigned*       Pbot   = (unsigned*)(ws + p_sz);
    unsigned short* row16  = (unsigned short*)(ws + 2 * p_sz);
    int*            rowptr = (int*)(ws + 2 * p_sz + e16_sz);

    int gemm_blocks = (n_nodes + 63) / 64;
    int rp_blocks   = (n_nodes + 256) / 256;     // v in [0, n_nodes]
    int r16_blocks  = (n_edges + 2047) / 2048;   // 8 edges/thread

    precompute_kernel<<<gemm_blocks + rp_blocks + r16_blocks, 256, 0, stream>>>(
        embed, W1, b1, Ptop, Pbot, col, row, rowptr, row16,
        n_nodes, n_edges, gemm_blocks, rp_blocks);

    // cooperative edge+symmetrize: grid sized to guaranteed co-residency
    int dev = 0;
    hipGetDevice(&dev);
    int cus = 256;
    hipDeviceGetAttribute(&cus, hipDeviceAttributeMultiprocessorCount, dev);
    int nb = 1;
    hipOccupancyMaxActiveBlocksPerMultiprocessor(
        &nb, (const void*)edge_sym_kernel, 256, 0);
    if (nb < 1) nb = 1;
    int maxb = (n_edges + 255) / 256;
    int gridb = cus * nb;
    if (gridb > maxb) gridb = maxb;

    const uint4* Ptop4 = (const uint4*)Ptop;
    const uint4* Pbot4 = (const uint4*)Pbot;
    const unsigned short* row16c = row16;
    const int* rowptrc = rowptr;
    float inv_n = 1.0f / (float)n_nodes;
    void* args[] = {
        (void*)&Ptop4, (void*)&Pbot4, (void*)&W2, (void*)&b2, (void*)&noise,
        (void*)&col, (void*)&row16c, (void*)&rowptrc, (void*)&out,
        (void*)&n_edges, (void*)&inv_n,
    };
    hipLaunchCooperativeKernel((const void*)edge_sym_kernel,
                               dim3(gridb), dim3(256), args, 0, stream);
}

// Round 18
// 61.460 us; speedup vs baseline: 4.3895x; 4.3895x over previous
//
#include <hip/hip_runtime.h>
#include <hip/hip_bf16.h>

// PGExplainer edge mask.  (R18 = R15 verbatim restore — best known, 61.7µs.
//  FAILED experiments, do not retry: R10 same-time fusion (random-set union
//  8.5MB > 4MB XCD L2 -> 87MB HBM), R11 2-edge/thread edge_value, R12 Bloom
//  atomicOr bitmap (53MB atomic write-back), R16 nontemporal hints (+6µs),
//  R17 cooperative grid.sync fusion (269µs: capped grid + cross-XCD sync).)
//  1) f12@W1 factorized: P_top = embed@W1[:64]+b1, P_bot = embed@W1[64:]
//     (LDS-tiled fp32 GEMM; k-loop unroll LIMITED to 2 — full spills).
//  2) keys (col*n+row) sorted ascending (np.unique) -> argsort is identity.
//     Reverse lookup via CSR rowptr + interpolation-guess + local scan.
//  3) sigmoid(log(u)-log1p(-u)+la) == u / (u + (1-u)*exp(-la)).
//  4) Per-kernel random-gather footprint kept under the 4 MB per-XCD L2:
//     - edge_value: Pbot fp8 (2.56 MB random; Ptop streams w/ sorted col)
//     - symmetrize: row16 u16 probes (3.2 MB); out[] read only on match.
//  5) Pair-canonical symmetrize: only c<r searches; matches (~800 pairs)
//     exchange fp32 values directly through out[] (disjoint, race-free).

typedef __attribute__((ext_vector_type(2))) float f32x2;

#define EPAD 68   // embed-tile row stride (floats): 16B-aligned, bank-spread

__global__ __launch_bounds__(256) void precompute_kernel(
        const float* __restrict__ embed,
        const float* __restrict__ W1,
        const float* __restrict__ b1,
        unsigned* __restrict__ Ptop,          // fp8 e4m3, 16 u32 per node
        unsigned* __restrict__ Pbot,          // fp8 e4m3, 16 u32 per node
        int n_nodes) {
    int t = threadIdx.x;

    __shared__ float W1s[128 * 64];     // 32 KB
    __shared__ float E[64 * EPAD];      // 17.4 KB
    int base = blockIdx.x * 64;

#pragma unroll
    for (int i = 0; i < 8; ++i) {
        int idx = i * 256 + t;
        ((float4*)W1s)[idx] = ((const float4*)W1)[idx];
    }
#pragma unroll
    for (int i = 0; i < 4; ++i) {
        int fi = i * 256 + t;
        int n = fi >> 4;
        int k4 = (fi & 15) * 4;
        float4 v;
        if (base + n < n_nodes)
            v = ((const float4*)(embed + (size_t)(base + n) * 64))[fi & 15];
        else
            v = make_float4(0.f, 0.f, 0.f, 0.f);
        *((float4*)(E + n * EPAD + k4)) = v;
    }
    __syncthreads();

    int tj = t & 15, tn = t >> 4;
    int j4 = tj * 4, n4 = tn * 4;
    float4 b1v = *(const float4*)(b1 + j4);
    float4 at[4], ab[4];
#pragma unroll
    for (int i = 0; i < 4; ++i) {
        at[i] = b1v;
        ab[i] = make_float4(0.f, 0.f, 0.f, 0.f);
    }

    // unroll 2 ONLY: full unroll hoists ~768 floats of LDS loads -> spill
#pragma unroll 2
    for (int k4 = 0; k4 < 64; k4 += 4) {
        float4 e[4], wt[4], wb[4];
#pragma unroll
        for (int i = 0; i < 4; ++i) {
            e[i]  = *(const float4*)(E + (n4 + i) * EPAD + k4);
            wt[i] = *(const float4*)(W1s + (k4 + i) * 64 + j4);
            wb[i] = *(const float4*)(W1s + (64 + k4 + i) * 64 + j4);
        }
#pragma unroll
        for (int n = 0; n < 4; ++n) {
#pragma unroll
            for (int kk = 0; kk < 4; ++kk) {
                float ev = (kk == 0) ? e[n].x : (kk == 1) ? e[n].y
                         : (kk == 2) ? e[n].z : e[n].w;
                at[n].x += ev * wt[kk].x;  at[n].y += ev * wt[kk].y;
                at[n].z += ev * wt[kk].z;  at[n].w += ev * wt[kk].w;
                ab[n].x += ev * wb[kk].x;  ab[n].y += ev * wb[kk].y;
                ab[n].z += ev * wb[kk].z;  ab[n].w += ev * wb[kk].w;
            }
        }
    }

#pragma unroll
    for (int i = 0; i < 4; ++i) {
        int node = base + n4 + i;
        if (node >= n_nodes) break;
        int wt8 = __builtin_amdgcn_cvt_pk_fp8_f32(at[i].x, at[i].y, 0, false);
        wt8     = __builtin_amdgcn_cvt_pk_fp8_f32(at[i].z, at[i].w, wt8, true);
        Ptop[(size_t)node * 16 + tj] = (unsigned)wt8;
        int wb8 = __builtin_amdgcn_cvt_pk_fp8_f32(ab[i].x, ab[i].y, 0, false);
        wb8     = __builtin_amdgcn_cvt_pk_fp8_f32(ab[i].z, ab[i].w, wb8, true);
        Pbot[(size_t)node * 16 + tj] = (unsigned)wb8;
    }
}

// 4 relu-dot terms from one fp8-quad word per side, packed f32x2 math
#define DOTW(au, bu, wp, acc0, acc1) do {                             \
    f32x2 alo = __builtin_amdgcn_cvt_pk_f32_fp8((au), false);         \
    f32x2 ahi = __builtin_amdgcn_cvt_pk_f32_fp8((au), true);          \
    f32x2 blo = __builtin_amdgcn_cvt_pk_f32_fp8((bu), false);         \
    f32x2 bhi = __builtin_amdgcn_cvt_pk_f32_fp8((bu), true);          \
    f32x2 s0 = alo + blo, s1 = ahi + bhi;                             \
    s0 = __builtin_elementwise_max(s0, (f32x2)0.f);                   \
    s1 = __builtin_elementwise_max(s1, (f32x2)0.f);                   \
    acc0 += s0 * ((const f32x2*)(wp))[0];                             \
    acc1 += s1 * ((const f32x2*)(wp))[1];                             \
} while (0)

__global__ __launch_bounds__(256) void edge_value_kernel(
        const uint4* __restrict__ Ptop,   // fp8x16 per node
        const uint4* __restrict__ Pbot,
        const float* __restrict__ W2,
        const float* __restrict__ b2,
        const float* __restrict__ noise,
        const int* __restrict__ col,
        const int* __restrict__ row,
        unsigned short* __restrict__ row16,
        float* __restrict__ out,
        int* __restrict__ rowptr,
        int n_edges, int n_nodes, int rp_blocks) {
    int t = threadIdx.x;
    int bid = blockIdx.x;

    if (bid < rp_blocks) {
        // ---- rowptr duty (consumed only by symmetrize) ----
        int v = bid * 256 + t;
        if (v <= n_nodes) {
            int lo = 0, hi = n_edges;
            while (lo < hi) {
                int mid = (lo + hi) >> 1;
                if (col[mid] < v) lo = mid + 1; else hi = mid;
            }
            rowptr[v] = lo;
        }
        return;
    }

    int e = (bid - rp_blocks) * 256 + t;
    if (e >= n_edges) return;
    int c = col[e], r = row[e];
    const uint4* pt = Ptop + (size_t)c * 4;
    const uint4* pb = Pbot + (size_t)r * 4;
    f32x2 acc0 = {b2[0], 0.f}, acc1 = {0.f, 0.f};
    f32x2 acc2 = {0.f, 0.f},  acc3 = {0.f, 0.f};
#pragma unroll
    for (int g = 0; g < 4; ++g) {
        uint4 a = pt[g];
        uint4 b = pb[g];
        const float* w = W2 + g * 16;
        DOTW(a.x, b.x, w,      acc0, acc1);
        DOTW(a.y, b.y, w + 4,  acc2, acc3);
        DOTW(a.z, b.z, w + 8,  acc0, acc1);
        DOTW(a.w, b.w, w + 12, acc2, acc3);
    }
    f32x2 acc = (acc0 + acc1) + (acc2 + acc3);
    float la = acc.x + acc.y;
    float u = noise[e];
    float v = u / (u + (1.f - u) * __expf(-la));
    row16[e] = (unsigned short)r;
    // diagonal (c==r) is its own reverse: v_sym = (v+v)/2 = v
    out[e] = (c == r) ? v : 0.5f * v;
}

__global__ __launch_bounds__(256) void symmetrize_kernel(
        const int* __restrict__ col,
        const unsigned short* __restrict__ row16,
        const int* __restrict__ rowptr,
        float* __restrict__ out,
        int n_edges, float inv_n) {
    int t = threadIdx.x;
    int e0 = blockIdx.x * 1024 + t;
    int c[4], r[4], lo[4], hi[4], g[4], pr[4];
    bool act[4], s[4];

    // phase 1: streaming loads (4 edges); canonical side only (c < r)
#pragma unroll
    for (int i = 0; i < 4; ++i) {
        int e = e0 + i * 256;
        bool p = e < n_edges;
        c[i] = 0; r[i] = -1;
        if (p) { c[i] = col[e]; r[i] = row16[e]; }
        act[i] = p && c[i] < r[i];
    }
    // phase 2: rowptr pairs (random 8B in 160KB, L2-resident)
#pragma unroll
    for (int i = 0; i < 4; ++i) {
        lo[i] = 0; hi[i] = 0;
        if (act[i]) { lo[i] = rowptr[r[i]]; hi[i] = rowptr[r[i] + 1]; }
    }
    // phase 3: interpolation guesses + initial probes
#pragma unroll
    for (int i = 0; i < 4; ++i) {
        s[i] = act[i] && hi[i] > lo[i];
        g[i] = 0; pr[i] = 0;
        if (s[i]) {
            g[i] = lo[i] + (int)((float)c[i] * (float)(hi[i] - lo[i]) * inv_n);
            if (g[i] >= hi[i]) g[i] = hi[i] - 1;
            pr[i] = row16[g[i]];
        }
    }
    // phase 4: local scans; on match (~800 pairs total) exchange through
    // out[] (fp32 exact). Partner is non-canonical -> never writes here;
    // pairs disjoint; edge_value completed -> race-free, deterministic.
#pragma unroll
    for (int i = 0; i < 4; ++i) {
        if (!s[i]) continue;
        int gg = g[i], rv = pr[i], hh = hi[i], ll = lo[i], cc = c[i];
        int match = -1;
        if (rv < cc) {
            while (++gg < hh) { rv = row16[gg]; if (rv >= cc) break; }
            if (gg < hh && rv == cc) match = gg;
        } else {
            while (rv > cc && gg > ll) rv = row16[--gg];
            if (rv == cc) match = gg;
        }
        if (match >= 0) {
            int e = e0 + i * 256;
            float mine   = out[e];        // 0.5 * v_fwd
            float theirs = out[match];    // 0.5 * v_rev
            out[e]     = mine + theirs;
            out[match] = theirs + mine;
        }
    }
}

extern "C" void kernel_launch(void* const* d_in, const int* in_sizes, int n_in,
                              void* d_out, int out_size, void* d_ws, size_t ws_size,
                              hipStream_t stream) {
    const float* embed = (const float*)d_in[0];
    const float* W1    = (const float*)d_in[1];
    const float* b1    = (const float*)d_in[2];
    const float* W2    = (const float*)d_in[3];
    const float* b2    = (const float*)d_in[4];
    const float* noise = (const float*)d_in[5];
    const int*   col   = (const int*)d_in[6];
    const int*   row   = (const int*)d_in[7];

    int n_nodes = in_sizes[0] / 64;   // 40000
    int n_edges = in_sizes[5];        // 1600000
    float* out = (float*)d_out;

    char* ws = (char*)d_ws;
    size_t p_sz   = (size_t)n_nodes * 16 * sizeof(unsigned);   // 2.56 MB each
    size_t e16_sz = (size_t)n_edges * sizeof(unsigned short);  // 3.2 MB
    unsigned*       Ptop   = (unsigned*)ws;
    unsigned*       Pbot   = (unsigned*)(ws + p_sz);
    unsigned short* row16  = (unsigned short*)(ws + 2 * p_sz);
    int*            rowptr = (int*)(ws + 2 * p_sz + e16_sz);

    int gemm_blocks = (n_nodes + 63) / 64;
    int rp_blocks   = (n_nodes + 256) / 256;   // covers v in [0, n_nodes]

    precompute_kernel<<<gemm_blocks, 256, 0, stream>>>(
        embed, W1, b1, Ptop, Pbot, n_nodes);

    edge_value_kernel<<<rp_blocks + (n_edges + 255) / 256, 256, 0, stream>>>(
        (const uint4*)Ptop, (const uint4*)Pbot, W2, b2, noise, col, row,
        row16, out, rowptr, n_edges, n_nodes, rp_blocks);

    symmetrize_kernel<<<(n_edges + 1023) / 1024, 256, 0, stream>>>(
        col, row16, rowptr, out, n_edges, 1.0f / (float)n_nodes);
}